// Round 1
// baseline (745.870 us; speedup 1.0000x reference)
//
#include <hip/hip_runtime.h>
#include <math.h>

#define NN 50000
#define NE 800000
#define NG 64
#define FIN 128
#define FH 256      // heads * HID = 4*64, both layers
#define HID 64
#define NH 4
#define NOUT 10
#define NEG_SLOPE 0.2f

static __device__ __forceinline__ float leaky(float x){ return x > 0.f ? x : NEG_SLOPE * x; }
static __device__ __forceinline__ float elu1(float x){ return x > 0.f ? x : (__expf(x) - 1.f); }

// ---------------- CSR build ----------------
__global__ void k_hist(const int* __restrict__ dst, int* __restrict__ cnt){
  int i = blockIdx.x * blockDim.x + threadIdx.x;
  if (i < NE) atomicAdd(&cnt[dst[i]], 1);
}

__global__ void k_scan(const int* __restrict__ cnt, int* __restrict__ offs){
  __shared__ int sums[1024];
  int t = threadIdx.x;
  const int CH = (NN + 1023) / 1024;
  int base = t * CH;
  int s = 0;
  for (int j = 0; j < CH; j++){
    int idx = base + j;
    if (idx < NN) s += cnt[idx];
  }
  sums[t] = s;
  __syncthreads();
  for (int d = 1; d < 1024; d <<= 1){
    int v = (t >= d) ? sums[t - d] : 0;
    __syncthreads();
    sums[t] += v;
    __syncthreads();
  }
  int run = (t == 0) ? 0 : sums[t - 1];
  for (int j = 0; j < CH; j++){
    int idx = base + j;
    if (idx < NN){ offs[idx] = run; run += cnt[idx]; }
  }
  if (t == 0) offs[NN] = NE;
}

__global__ void k_scatter(const int* __restrict__ src, const int* __restrict__ dst,
                          const int* __restrict__ offs, int* __restrict__ cur,
                          int* __restrict__ csrc){
  int i = blockIdx.x * blockDim.x + threadIdx.x;
  if (i < NE){
    int d = dst[i];
    int pos = offs[d] + atomicAdd(&cur[d], 1);
    csrc[pos] = src[i];
  }
}

// ---------------- fp32 tiled GEMM: C[M,NC] = A[M,K] @ B[K,NC] ----------------
__global__ __launch_bounds__(256) void k_gemm(const float* __restrict__ A,
    const float* __restrict__ B, float* __restrict__ C, int M, int K, int NC)
{
  __shared__ float As[32][64];   // As[k][m] (transposed)
  __shared__ float Bs[32][64];   // Bs[k][n]
  int bm = blockIdx.x * 64, bn = blockIdx.y * 64;
  int t = threadIdx.x;
  int tx = t & 15, ty = t >> 4;
  float acc[4][4] = {{0.f}};
  for (int k0 = 0; k0 < K; k0 += 32){
    #pragma unroll
    for (int l = 0; l < 2; l++){
      int idx = t + l * 256;     // 0..511: 64 rows x 8 float4
      int r = idx >> 3, c4 = idx & 7;
      float4 v = make_float4(0.f, 0.f, 0.f, 0.f);
      int row = bm + r;
      if (row < M) v = *reinterpret_cast<const float4*>(&A[(size_t)row * K + k0 + c4 * 4]);
      As[c4 * 4 + 0][r] = v.x; As[c4 * 4 + 1][r] = v.y;
      As[c4 * 4 + 2][r] = v.z; As[c4 * 4 + 3][r] = v.w;
    }
    #pragma unroll
    for (int l = 0; l < 2; l++){
      int idx = t + l * 256;     // 0..511: 32 rows x 16 float4
      int r = idx >> 4, c4 = idx & 15;
      float4 v = *reinterpret_cast<const float4*>(&B[(size_t)(k0 + r) * NC + bn + c4 * 4]);
      *reinterpret_cast<float4*>(&Bs[r][c4 * 4]) = v;
    }
    __syncthreads();
    #pragma unroll
    for (int kk = 0; kk < 32; kk++){
      float4 av = *reinterpret_cast<const float4*>(&As[kk][ty * 4]);
      float4 bv = *reinterpret_cast<const float4*>(&Bs[kk][tx * 4]);
      float a[4] = {av.x, av.y, av.z, av.w};
      float b[4] = {bv.x, bv.y, bv.z, bv.w};
      #pragma unroll
      for (int i = 0; i < 4; i++)
        #pragma unroll
        for (int j = 0; j < 4; j++)
          acc[i][j] = fmaf(a[i], b[j], acc[i][j]);
    }
    __syncthreads();
  }
  #pragma unroll
  for (int i = 0; i < 4; i++){
    int row = bm + ty * 4 + i;
    if (row < M){
      float4 o = make_float4(acc[i][0], acc[i][1], acc[i][2], acc[i][3]);
      *reinterpret_cast<float4*>(&C[(size_t)row * NC + bn + tx * 4]) = o;
    }
  }
}

// ---------------- attention scores: el/er [N,4] ----------------
__global__ __launch_bounds__(256) void k_scores(const float* __restrict__ feat,
    const float* __restrict__ attn_l, const float* __restrict__ attn_r,
    float* __restrict__ el, float* __restrict__ er)
{
  int wv = threadIdx.x >> 6, lane = threadIdx.x & 63;
  int n = blockIdx.x * 4 + wv;
  if (n >= NN) return;
  float4 f  = *reinterpret_cast<const float4*>(&feat[(size_t)n * FH + lane * 4]);
  float4 al = *reinterpret_cast<const float4*>(&attn_l[lane * 4]);
  float4 ar = *reinterpret_cast<const float4*>(&attn_r[lane * 4]);
  float pl = f.x * al.x + f.y * al.y + f.z * al.z + f.w * al.w;
  float pr = f.x * ar.x + f.y * ar.y + f.z * ar.z + f.w * ar.w;
  #pragma unroll
  for (int d = 1; d < 16; d <<= 1){
    pl += __shfl_xor(pl, d);
    pr += __shfl_xor(pr, d);
  }
  if ((lane & 15) == 0){
    el[n * 4 + (lane >> 4)] = pl;
    er[n * 4 + (lane >> 4)] = pr;
  }
}

// ---------------- per-dst-node attention softmax + aggregation ----------------
// One wave per dst node. LAYER 1: out[N,256] = elu(agg+b) (flatten heads)
// LAYER 2: out[N,64] = mean over heads of elu(agg+b)
template<int LAYER>
__global__ __launch_bounds__(256) void k_agg(const float* __restrict__ feat,
    const float* __restrict__ el, const float* __restrict__ er,
    const int* __restrict__ offs, const int* __restrict__ csrc,
    const float* __restrict__ bias, float* __restrict__ out)
{
  __shared__ volatile float s_ex[4][64][4];
  __shared__ volatile int   s_src[4][64];
  int wv = threadIdx.x >> 6, lane = threadIdx.x & 63;
  int n = blockIdx.x * 4 + wv;
  if (n >= NN) return;
  int e0 = offs[n];
  int deg = offs[n + 1] - e0;
  int h = lane >> 4;
  float4 er4 = *reinterpret_cast<const float4*>(&er[n * 4]);

  // phase 1: per-head max over edges
  float m0 = -INFINITY, m1 = -INFINITY, m2 = -INFINITY, m3 = -INFINITY;
  for (int j = lane; j < deg; j += 64){
    int s = csrc[e0 + j];
    float4 l4 = *reinterpret_cast<const float4*>(&el[s * 4]);
    m0 = fmaxf(m0, leaky(l4.x + er4.x));
    m1 = fmaxf(m1, leaky(l4.y + er4.y));
    m2 = fmaxf(m2, leaky(l4.z + er4.z));
    m3 = fmaxf(m3, leaky(l4.w + er4.w));
  }
  #pragma unroll
  for (int d = 1; d < 64; d <<= 1){
    m0 = fmaxf(m0, __shfl_xor(m0, d));
    m1 = fmaxf(m1, __shfl_xor(m1, d));
    m2 = fmaxf(m2, __shfl_xor(m2, d));
    m3 = fmaxf(m3, __shfl_xor(m3, d));
  }
  // phase 2: per-head sum of exp
  float s0 = 0.f, s1 = 0.f, s2 = 0.f, s3 = 0.f;
  for (int j = lane; j < deg; j += 64){
    int s = csrc[e0 + j];
    float4 l4 = *reinterpret_cast<const float4*>(&el[s * 4]);
    s0 += __expf(leaky(l4.x + er4.x) - m0);
    s1 += __expf(leaky(l4.y + er4.y) - m1);
    s2 += __expf(leaky(l4.z + er4.z) - m2);
    s3 += __expf(leaky(l4.w + er4.w) - m3);
  }
  #pragma unroll
  for (int d = 1; d < 64; d <<= 1){
    s0 += __shfl_xor(s0, d);
    s1 += __shfl_xor(s1, d);
    s2 += __shfl_xor(s2, d);
    s3 += __shfl_xor(s3, d);
  }
  float sh = (h == 0) ? s0 : (h == 1) ? s1 : (h == 2) ? s2 : s3;
  float inv = 1.f / sh;   // deg==0 -> inf, unused

  // phase 3: weighted aggregation, chunked by 64 edges
  float a0 = 0.f, a1 = 0.f, a2 = 0.f, a3 = 0.f;
  for (int base = 0; base < deg; base += 64){
    int cnt = min(64, deg - base);
    if (lane < cnt){
      int s = csrc[e0 + base + lane];
      float4 l4 = *reinterpret_cast<const float4*>(&el[s * 4]);
      s_src[wv][lane] = s;
      s_ex[wv][lane][0] = __expf(leaky(l4.x + er4.x) - m0);
      s_ex[wv][lane][1] = __expf(leaky(l4.y + er4.y) - m1);
      s_ex[wv][lane][2] = __expf(leaky(l4.z + er4.z) - m2);
      s_ex[wv][lane][3] = __expf(leaky(l4.w + er4.w) - m3);
    }
    for (int jj = 0; jj < cnt; jj++){
      int sj = s_src[wv][jj];
      float al = s_ex[wv][jj][h] * inv;
      float4 f = *reinterpret_cast<const float4*>(&feat[(size_t)sj * FH + lane * 4]);
      a0 = fmaf(al, f.x, a0);
      a1 = fmaf(al, f.y, a1);
      a2 = fmaf(al, f.z, a2);
      a3 = fmaf(al, f.w, a3);
    }
  }

  float4 bv = *reinterpret_cast<const float4*>(&bias[lane * 4]);
  a0 = elu1(a0 + bv.x); a1 = elu1(a1 + bv.y);
  a2 = elu1(a2 + bv.z); a3 = elu1(a3 + bv.w);

  if (LAYER == 1){
    float4 o = make_float4(a0, a1, a2, a3);
    *reinterpret_cast<float4*>(&out[(size_t)n * FH + lane * 4]) = o;
  } else {
    a0 += __shfl_xor(a0, 16); a0 += __shfl_xor(a0, 32);
    a1 += __shfl_xor(a1, 16); a1 += __shfl_xor(a1, 32);
    a2 += __shfl_xor(a2, 16); a2 += __shfl_xor(a2, 32);
    a3 += __shfl_xor(a3, 16); a3 += __shfl_xor(a3, 32);
    if (lane < 16){
      float4 o = make_float4(a0 * 0.25f, a1 * 0.25f, a2 * 0.25f, a3 * 0.25f);
      *reinterpret_cast<float4*>(&out[(size_t)n * HID + lane * 4]) = o;
    }
  }
}

// ---------------- graph sum-pooling (graph_ids sorted) ----------------
__global__ __launch_bounds__(256) void k_pool(const float* __restrict__ h2,
    const int* __restrict__ gid, float* __restrict__ pooled)
{
  int wv = threadIdx.x >> 6, lane = threadIdx.x & 63;
  int base = blockIdx.x * 1024;
  int curg = -1; float acc = 0.f;
  for (int i = wv; i < 1024; i += 4){
    int nn = base + i;
    if (nn >= NN) break;
    int g = gid[nn];
    if (g != curg){
      if (curg >= 0) atomicAdd(&pooled[curg * HID + lane], acc);
      curg = g; acc = 0.f;
    }
    acc += h2[(size_t)nn * HID + lane];
  }
  if (curg >= 0) atomicAdd(&pooled[curg * HID + lane], acc);
}

// ---------------- final FC: out[64,10] = pooled @ fcW + fcb ----------------
__global__ void k_fc(const float* __restrict__ pooled, const float* __restrict__ fcW,
                     const float* __restrict__ fcb, float* __restrict__ out)
{
  int t = threadIdx.x;
  if (t >= NG * NOUT) return;
  int g = t / NOUT, o = t % NOUT;
  float s = fcb[o];
  for (int d = 0; d < HID; d++) s = fmaf(pooled[g * HID + d], fcW[d * NOUT + o], s);
  out[t] = s;
}

static inline size_t align_up(size_t x){ return (x + 255) & ~(size_t)255; }

extern "C" void kernel_launch(void* const* d_in, const int* in_sizes, int n_in,
                              void* d_out, int out_size, void* d_ws, size_t ws_size,
                              hipStream_t stream) {
  const float* x    = (const float*)d_in[0];
  const int*   src  = (const int*)d_in[1];
  const int*   dst  = (const int*)d_in[2];
  const int*   gid  = (const int*)d_in[3];
  const float* W1   = (const float*)d_in[4];
  const float* al1  = (const float*)d_in[5];
  const float* ar1  = (const float*)d_in[6];
  const float* b1   = (const float*)d_in[7];
  const float* W2   = (const float*)d_in[8];
  const float* al2  = (const float*)d_in[9];
  const float* ar2  = (const float*)d_in[10];
  const float* b2   = (const float*)d_in[11];
  const float* fcW  = (const float*)d_in[12];
  const float* fcb  = (const float*)d_in[13];
  float* out = (float*)d_out;

  char* p = (char*)d_ws;
  int* cnt  = (int*)p; p += align_up((size_t)NN * 4);
  int* cur  = (int*)p; p += align_up((size_t)NN * 4);
  int* offs = (int*)p; p += align_up((size_t)(NN + 1) * 4);
  int* csrc = (int*)p; p += align_up((size_t)NE * 4);
  float* featA  = (float*)p; p += align_up((size_t)NN * FH * 4);
  float* h1     = (float*)p; p += align_up((size_t)NN * FH * 4);
  float* elb    = (float*)p; p += align_up((size_t)NN * NH * 4);
  float* erb    = (float*)p; p += align_up((size_t)NN * NH * 4);
  float* h2     = (float*)p; p += align_up((size_t)NN * HID * 4);
  float* pooled = (float*)p; p += align_up((size_t)NG * HID * 4);

  // zero histogram + cursor (contiguous)
  hipMemsetAsync(cnt, 0, (size_t)((char*)offs - (char*)cnt), stream);

  const int EB = (NE + 255) / 256;      // 3125
  const int NB4 = (NN + 3) / 4;         // 12500

  k_hist<<<EB, 256, 0, stream>>>(dst, cnt);
  k_scan<<<1, 1024, 0, stream>>>(cnt, offs);
  k_scatter<<<EB, 256, 0, stream>>>(src, dst, offs, cur, csrc);

  // layer 1
  k_gemm<<<dim3((NN + 63) / 64, FH / 64), 256, 0, stream>>>(x, W1, featA, NN, FIN, FH);
  k_scores<<<NB4, 256, 0, stream>>>(featA, al1, ar1, elb, erb);
  k_agg<1><<<NB4, 256, 0, stream>>>(featA, elb, erb, offs, csrc, b1, h1);

  // layer 2
  k_gemm<<<dim3((NN + 63) / 64, FH / 64), 256, 0, stream>>>(h1, W2, featA, NN, FH, FH);
  k_scores<<<NB4, 256, 0, stream>>>(featA, al2, ar2, elb, erb);
  k_agg<2><<<NB4, 256, 0, stream>>>(featA, elb, erb, offs, csrc, b2, h2);

  // pooling + FC
  hipMemsetAsync(pooled, 0, (size_t)NG * HID * 4, stream);
  k_pool<<<(NN + 1023) / 1024, 256, 0, stream>>>(h2, gid, pooled);
  k_fc<<<1, 640, 0, stream>>>(pooled, fcW, fcb, out);
}

// Round 2
// 724.535 us; speedup vs baseline: 1.0294x; 1.0294x over previous
//
#include <hip/hip_runtime.h>
#include <math.h>

#define NN 50000
#define NE 800000
#define NG 64
#define FIN 128
#define FH 256      // heads * HID = 4*64, both layers
#define HID 64
#define NH 4
#define NOUT 10
#define NEG_SLOPE 0.2f

typedef unsigned short u16;
typedef __attribute__((ext_vector_type(8))) short short8;
typedef __attribute__((ext_vector_type(4))) float f32x4;

static __device__ __forceinline__ float leaky(float x){ return x > 0.f ? x : NEG_SLOPE * x; }
static __device__ __forceinline__ float elu1(float x){ return x > 0.f ? x : (__expf(x) - 1.f); }
static __device__ __forceinline__ float b2f(u16 u){
  union { unsigned int i; float f; } v; v.i = ((unsigned)u) << 16; return v.f;
}
static __device__ __forceinline__ u16 f2b(float f){
  union { float f; unsigned int i; } v; v.f = f;
  unsigned r = v.i + 0x7FFFu + ((v.i >> 16) & 1u);
  return (u16)(r >> 16);
}

// ---------------- CSR build ----------------
__global__ void k_hist(const int* __restrict__ dst, int* __restrict__ cnt){
  int i = blockIdx.x * blockDim.x + threadIdx.x;
  if (i < NE) atomicAdd(&cnt[dst[i]], 1);
}

__global__ void k_scan(const int* __restrict__ cnt, int* __restrict__ offs){
  __shared__ int sums[1024];
  int t = threadIdx.x;
  const int CH = (NN + 1023) / 1024;
  int base = t * CH;
  int s = 0;
  for (int j = 0; j < CH; j++){
    int idx = base + j;
    if (idx < NN) s += cnt[idx];
  }
  sums[t] = s;
  __syncthreads();
  for (int d = 1; d < 1024; d <<= 1){
    int v = (t >= d) ? sums[t - d] : 0;
    __syncthreads();
    sums[t] += v;
    __syncthreads();
  }
  int run = (t == 0) ? 0 : sums[t - 1];
  for (int j = 0; j < CH; j++){
    int idx = base + j;
    if (idx < NN){ offs[idx] = run; run += cnt[idx]; }
  }
  if (t == 0) offs[NN] = NE;
}

__global__ void k_scatter(const int* __restrict__ src, const int* __restrict__ dst,
                          const int* __restrict__ offs, int* __restrict__ cur,
                          int* __restrict__ csrc){
  int i = blockIdx.x * blockDim.x + threadIdx.x;
  if (i < NE){
    int d = dst[i];
    int pos = offs[d] + atomicAdd(&cur[d], 1);
    csrc[pos] = src[i];
  }
}

// ---------------- fp32 -> bf16 conversion ----------------
__global__ void k_f2b(const float* __restrict__ in, u16* __restrict__ out, int n){
  int i = (blockIdx.x * 256 + threadIdx.x) * 4;
  if (i >= n) return;
  float4 v = *reinterpret_cast<const float4*>(in + i);
  ushort4 o; o.x = f2b(v.x); o.y = f2b(v.y); o.z = f2b(v.z); o.w = f2b(v.w);
  *reinterpret_cast<ushort4*>(out + i) = o;
}

// W [K][256] fp32 -> transposed split Wth/Wtl [256][K] bf16 (hi + residual)
__global__ void k_wsplit(const float* __restrict__ W, u16* __restrict__ Wth,
                         u16* __restrict__ Wtl, int K){
  int e = blockIdx.x * 256 + threadIdx.x;
  if (e >= K * 256) return;
  int k = e >> 8, c = e & 255;
  float w = W[e];
  u16 hi = f2b(w);
  float lo = w - b2f(hi);
  Wth[c * K + k] = hi;
  Wtl[c * K + k] = f2b(lo);
}

// ---------------- bf16 MFMA GEMM: C[M,256] = A[M,K] @ B, B given as Bt[256][K] hi+lo ----------------
__global__ __launch_bounds__(256) void k_gemm_bf(
    const u16* __restrict__ A, const u16* __restrict__ Bth,
    const u16* __restrict__ Btl, u16* __restrict__ C, int M, int K)
{
  __shared__ u16 sc[4][16][264];   // per-wave staging, +8 pad
  int wv = threadIdx.x >> 6, lane = threadIdx.x & 63;
  int strip = blockIdx.x * 4 + wv;
  int nstrip = M >> 4;
  if (strip >= nstrip) return;
  int row0 = strip * 16;
  int lr = lane & 15, lk = lane >> 4;   // A row / B col within tile, k-block
  f32x4 acc[16];
  #pragma unroll
  for (int t = 0; t < 16; t++) acc[t] = (f32x4){0.f, 0.f, 0.f, 0.f};
  const u16* Ab = A + (size_t)(row0 + lr) * K + lk * 8;
  #pragma unroll
  for (int pass = 0; pass < 2; pass++){
    const u16* Bb = (pass == 0 ? Bth : Btl) + (size_t)lr * K + lk * 8;
    for (int k0 = 0; k0 < K; k0 += 32){
      short8 a = *reinterpret_cast<const short8*>(Ab + k0);
      #pragma unroll
      for (int t = 0; t < 16; t++){
        short8 b = *reinterpret_cast<const short8*>(Bb + (size_t)t * 16 * K + k0);
        acc[t] = __builtin_amdgcn_mfma_f32_16x16x32_bf16(a, b, acc[t], 0, 0, 0);
      }
    }
  }
  // epilogue: C/D layout col=lane&15, row=(lane>>4)*4+reg  -> LDS -> coalesced bf16 store
  int rg = lane >> 4;
  #pragma unroll
  for (int t = 0; t < 16; t++)
    #pragma unroll
    for (int r = 0; r < 4; r++)
      sc[wv][rg * 4 + r][t * 16 + lr] = f2b(acc[t][r]);
  #pragma unroll
  for (int row = 0; row < 16; row++){
    ushort4 v = *reinterpret_cast<const ushort4*>(&sc[wv][row][lane * 4]);
    *reinterpret_cast<ushort4*>(C + (size_t)(row0 + row) * 256 + lane * 4) = v;
  }
}

// ---------------- attention scores from bf16 feat ----------------
__global__ __launch_bounds__(256) void k_scores_bf(const u16* __restrict__ feat,
    const float* __restrict__ attn_l, const float* __restrict__ attn_r,
    float* __restrict__ el, float* __restrict__ er)
{
  int wv = threadIdx.x >> 6, lane = threadIdx.x & 63;
  int n = blockIdx.x * 4 + wv;
  if (n >= NN) return;
  ushort4 f = *reinterpret_cast<const ushort4*>(feat + (size_t)n * FH + lane * 4);
  float4 al = *reinterpret_cast<const float4*>(&attn_l[lane * 4]);
  float4 ar = *reinterpret_cast<const float4*>(&attn_r[lane * 4]);
  float fx = b2f(f.x), fy = b2f(f.y), fz = b2f(f.z), fw = b2f(f.w);
  float pl = fx * al.x + fy * al.y + fz * al.z + fw * al.w;
  float pr = fx * ar.x + fy * ar.y + fz * ar.z + fw * ar.w;
  #pragma unroll
  for (int d = 1; d < 16; d <<= 1){
    pl += __shfl_xor(pl, d);
    pr += __shfl_xor(pr, d);
  }
  if ((lane & 15) == 0){
    el[n * 4 + (lane >> 4)] = pl;
    er[n * 4 + (lane >> 4)] = pr;
  }
}

// ---------------- per-dst-node attention softmax + aggregation (bf16 gather) ----------------
template<int LAYER>
__global__ __launch_bounds__(256) void k_agg(const u16* __restrict__ feat,
    const float* __restrict__ el, const float* __restrict__ er,
    const int* __restrict__ offs, const int* __restrict__ csrc,
    const float* __restrict__ bias, void* __restrict__ outv)
{
  __shared__ volatile float s_ex[4][64][4];
  __shared__ volatile int   s_src[4][64];
  int wv = threadIdx.x >> 6, lane = threadIdx.x & 63;
  int n = blockIdx.x * 4 + wv;
  if (n >= NN) return;
  int e0 = offs[n];
  int deg = offs[n + 1] - e0;
  int h = lane >> 4;
  float4 er4 = *reinterpret_cast<const float4*>(&er[n * 4]);

  float m0 = -INFINITY, m1 = -INFINITY, m2 = -INFINITY, m3 = -INFINITY;
  for (int j = lane; j < deg; j += 64){
    int s = csrc[e0 + j];
    float4 l4 = *reinterpret_cast<const float4*>(&el[s * 4]);
    m0 = fmaxf(m0, leaky(l4.x + er4.x));
    m1 = fmaxf(m1, leaky(l4.y + er4.y));
    m2 = fmaxf(m2, leaky(l4.z + er4.z));
    m3 = fmaxf(m3, leaky(l4.w + er4.w));
  }
  #pragma unroll
  for (int d = 1; d < 64; d <<= 1){
    m0 = fmaxf(m0, __shfl_xor(m0, d));
    m1 = fmaxf(m1, __shfl_xor(m1, d));
    m2 = fmaxf(m2, __shfl_xor(m2, d));
    m3 = fmaxf(m3, __shfl_xor(m3, d));
  }
  float s0 = 0.f, s1 = 0.f, s2 = 0.f, s3 = 0.f;
  for (int j = lane; j < deg; j += 64){
    int s = csrc[e0 + j];
    float4 l4 = *reinterpret_cast<const float4*>(&el[s * 4]);
    s0 += __expf(leaky(l4.x + er4.x) - m0);
    s1 += __expf(leaky(l4.y + er4.y) - m1);
    s2 += __expf(leaky(l4.z + er4.z) - m2);
    s3 += __expf(leaky(l4.w + er4.w) - m3);
  }
  #pragma unroll
  for (int d = 1; d < 64; d <<= 1){
    s0 += __shfl_xor(s0, d);
    s1 += __shfl_xor(s1, d);
    s2 += __shfl_xor(s2, d);
    s3 += __shfl_xor(s3, d);
  }
  float sh = (h == 0) ? s0 : (h == 1) ? s1 : (h == 2) ? s2 : s3;
  float inv = 1.f / sh;

  float a0 = 0.f, a1 = 0.f, a2 = 0.f, a3 = 0.f;
  for (int base = 0; base < deg; base += 64){
    int cnt = min(64, deg - base);
    if (lane < cnt){
      int s = csrc[e0 + base + lane];
      float4 l4 = *reinterpret_cast<const float4*>(&el[s * 4]);
      s_src[wv][lane] = s;
      s_ex[wv][lane][0] = __expf(leaky(l4.x + er4.x) - m0);
      s_ex[wv][lane][1] = __expf(leaky(l4.y + er4.y) - m1);
      s_ex[wv][lane][2] = __expf(leaky(l4.z + er4.z) - m2);
      s_ex[wv][lane][3] = __expf(leaky(l4.w + er4.w) - m3);
    }
    #pragma unroll 2
    for (int jj = 0; jj < cnt; jj++){
      int sj = s_src[wv][jj];
      float al_ = s_ex[wv][jj][h] * inv;
      ushort4 f = *reinterpret_cast<const ushort4*>(feat + (size_t)sj * FH + lane * 4);
      a0 = fmaf(al_, b2f(f.x), a0);
      a1 = fmaf(al_, b2f(f.y), a1);
      a2 = fmaf(al_, b2f(f.z), a2);
      a3 = fmaf(al_, b2f(f.w), a3);
    }
  }

  float4 bv = *reinterpret_cast<const float4*>(&bias[lane * 4]);
  a0 = elu1(a0 + bv.x); a1 = elu1(a1 + bv.y);
  a2 = elu1(a2 + bv.z); a3 = elu1(a3 + bv.w);

  if (LAYER == 1){
    u16* out = (u16*)outv;
    ushort4 o; o.x = f2b(a0); o.y = f2b(a1); o.z = f2b(a2); o.w = f2b(a3);
    *reinterpret_cast<ushort4*>(out + (size_t)n * FH + lane * 4) = o;
  } else {
    float* out = (float*)outv;
    a0 += __shfl_xor(a0, 16); a0 += __shfl_xor(a0, 32);
    a1 += __shfl_xor(a1, 16); a1 += __shfl_xor(a1, 32);
    a2 += __shfl_xor(a2, 16); a2 += __shfl_xor(a2, 32);
    a3 += __shfl_xor(a3, 16); a3 += __shfl_xor(a3, 32);
    if (lane < 16){
      float4 o = make_float4(a0 * 0.25f, a1 * 0.25f, a2 * 0.25f, a3 * 0.25f);
      *reinterpret_cast<float4*>(out + (size_t)n * HID + lane * 4) = o;
    }
  }
}

// ---------------- graph sum-pooling (graph_ids sorted) ----------------
__global__ __launch_bounds__(256) void k_pool(const float* __restrict__ h2,
    const int* __restrict__ gid, float* __restrict__ pooled)
{
  int wv = threadIdx.x >> 6, lane = threadIdx.x & 63;
  int base = blockIdx.x * 1024;
  int curg = -1; float acc = 0.f;
  for (int i = wv; i < 1024; i += 4){
    int nn = base + i;
    if (nn >= NN) break;
    int g = gid[nn];
    if (g != curg){
      if (curg >= 0) atomicAdd(&pooled[curg * HID + lane], acc);
      curg = g; acc = 0.f;
    }
    acc += h2[(size_t)nn * HID + lane];
  }
  if (curg >= 0) atomicAdd(&pooled[curg * HID + lane], acc);
}

// ---------------- final FC ----------------
__global__ void k_fc(const float* __restrict__ pooled, const float* __restrict__ fcW,
                     const float* __restrict__ fcb, float* __restrict__ out)
{
  int t = threadIdx.x;
  if (t >= NG * NOUT) return;
  int g = t / NOUT, o = t % NOUT;
  float s = fcb[o];
  for (int d = 0; d < HID; d++) s = fmaf(pooled[g * HID + d], fcW[d * NOUT + o], s);
  out[t] = s;
}

static inline size_t align_up(size_t x){ return (x + 255) & ~(size_t)255; }

extern "C" void kernel_launch(void* const* d_in, const int* in_sizes, int n_in,
                              void* d_out, int out_size, void* d_ws, size_t ws_size,
                              hipStream_t stream) {
  const float* x    = (const float*)d_in[0];
  const int*   src  = (const int*)d_in[1];
  const int*   dst  = (const int*)d_in[2];
  const int*   gid  = (const int*)d_in[3];
  const float* W1   = (const float*)d_in[4];
  const float* al1  = (const float*)d_in[5];
  const float* ar1  = (const float*)d_in[6];
  const float* b1   = (const float*)d_in[7];
  const float* W2   = (const float*)d_in[8];
  const float* al2  = (const float*)d_in[9];
  const float* ar2  = (const float*)d_in[10];
  const float* b2   = (const float*)d_in[11];
  const float* fcW  = (const float*)d_in[12];
  const float* fcb  = (const float*)d_in[13];
  float* out = (float*)d_out;

  char* p = (char*)d_ws;
  int* cnt  = (int*)p; p += align_up((size_t)NN * 4);
  int* cur  = (int*)p; p += align_up((size_t)NN * 4);
  int* offs = (int*)p; p += align_up((size_t)(NN + 1) * 4);
  int* csrc = (int*)p; p += align_up((size_t)NE * 4);
  u16* xh    = (u16*)p; p += align_up((size_t)NN * FIN * 2);
  u16* feath = (u16*)p; p += align_up((size_t)NN * FH * 2);
  u16* h1h   = (u16*)p; p += align_up((size_t)NN * FH * 2);
  float* elb = (float*)p; p += align_up((size_t)NN * NH * 4);
  float* erb = (float*)p; p += align_up((size_t)NN * NH * 4);
  float* h2  = (float*)p; p += align_up((size_t)NN * HID * 4);
  float* pooled = (float*)p; p += align_up((size_t)NG * HID * 4);
  u16* Wt1h = (u16*)p; p += align_up((size_t)FIN * FH * 2);
  u16* Wt1l = (u16*)p; p += align_up((size_t)FIN * FH * 2);
  u16* Wt2h = (u16*)p; p += align_up((size_t)FH * FH * 2);
  u16* Wt2l = (u16*)p; p += align_up((size_t)FH * FH * 2);

  hipMemsetAsync(cnt, 0, (size_t)((char*)offs - (char*)cnt), stream);

  const int EB = (NE + 255) / 256;      // 3125
  const int NB4 = (NN + 3) / 4;         // 12500
  const int GB = (NN / 16 + 3) / 4;     // 782

  k_hist<<<EB, 256, 0, stream>>>(dst, cnt);
  k_scan<<<1, 1024, 0, stream>>>(cnt, offs);
  k_scatter<<<EB, 256, 0, stream>>>(src, dst, offs, cur, csrc);

  k_f2b<<<(NN * FIN / 4 + 255) / 256, 256, 0, stream>>>(x, xh, NN * FIN);
  k_wsplit<<<(FIN * FH + 255) / 256, 256, 0, stream>>>(W1, Wt1h, Wt1l, FIN);
  k_wsplit<<<(FH * FH + 255) / 256, 256, 0, stream>>>(W2, Wt2h, Wt2l, FH);

  // layer 1
  k_gemm_bf<<<GB, 256, 0, stream>>>(xh, Wt1h, Wt1l, feath, NN, FIN);
  k_scores_bf<<<NB4, 256, 0, stream>>>(feath, al1, ar1, elb, erb);
  k_agg<1><<<NB4, 256, 0, stream>>>(feath, elb, erb, offs, csrc, b1, h1h);

  // layer 2
  k_gemm_bf<<<GB, 256, 0, stream>>>(h1h, Wt2h, Wt2l, feath, NN, FH);
  k_scores_bf<<<NB4, 256, 0, stream>>>(feath, al2, ar2, elb, erb);
  k_agg<2><<<NB4, 256, 0, stream>>>(feath, elb, erb, offs, csrc, b2, h2);

  // pooling + FC
  hipMemsetAsync(pooled, 0, (size_t)NG * HID * 4, stream);
  k_pool<<<(NN + 1023) / 1024, 256, 0, stream>>>(h2, gid, pooled);
  k_fc<<<1, 640, 0, stream>>>(pooled, fcW, fcb, out);
}

// Round 3
// 544.819 us; speedup vs baseline: 1.3690x; 1.3299x over previous
//
#include <hip/hip_runtime.h>
#include <math.h>

#define NN 50000
#define MPAD 50048   // 782 * 64
#define NE 800000
#define NG 64
#define FIN 128
#define FH 256      // heads * HID = 4*64, both layers
#define HID 64
#define NH 4
#define NOUT 10
#define NEG_SLOPE 0.2f

typedef unsigned short u16;
typedef __attribute__((ext_vector_type(8))) short short8;
typedef __attribute__((ext_vector_type(4))) float f32x4;

static __device__ __forceinline__ float leaky(float x){ return x > 0.f ? x : NEG_SLOPE * x; }
static __device__ __forceinline__ float elu1(float x){ return x > 0.f ? x : (__expf(x) - 1.f); }
static __device__ __forceinline__ float b2f(u16 u){
  union { unsigned int i; float f; } v; v.i = ((unsigned)u) << 16; return v.f;
}
static __device__ __forceinline__ u16 f2b(float f){
  union { float f; unsigned int i; } v; v.f = f;
  unsigned r = v.i + 0x7FFFu + ((v.i >> 16) & 1u);
  return (u16)(r >> 16);
}

static __device__ __forceinline__ void gl_lds16(const u16* g, u16* l){
  __builtin_amdgcn_global_load_lds(
      (const __attribute__((address_space(1))) void*)g,
      (__attribute__((address_space(3))) void*)l, 16, 0, 0);
}

// ---------------- CSR build ----------------
__global__ void k_hist(const int* __restrict__ dst, int* __restrict__ cnt){
  int i = blockIdx.x * blockDim.x + threadIdx.x;
  if (i < NE) atomicAdd(&cnt[dst[i]], 1);
}

__global__ void k_scan(const int* __restrict__ cnt, int* __restrict__ offs){
  __shared__ int sums[1024];
  int t = threadIdx.x;
  const int CH = (NN + 1023) / 1024;
  int base = t * CH;
  int s = 0;
  for (int j = 0; j < CH; j++){
    int idx = base + j;
    if (idx < NN) s += cnt[idx];
  }
  sums[t] = s;
  __syncthreads();
  for (int d = 1; d < 1024; d <<= 1){
    int v = (t >= d) ? sums[t - d] : 0;
    __syncthreads();
    sums[t] += v;
    __syncthreads();
  }
  int run = (t == 0) ? 0 : sums[t - 1];
  for (int j = 0; j < CH; j++){
    int idx = base + j;
    if (idx < NN){ offs[idx] = run; run += cnt[idx]; }
  }
  if (t == 0) offs[NN] = NE;
}

__global__ void k_scatter(const int* __restrict__ src, const int* __restrict__ dst,
                          const int* __restrict__ offs, int* __restrict__ cur,
                          int* __restrict__ csrc){
  int i = blockIdx.x * blockDim.x + threadIdx.x;
  if (i < NE){
    int d = dst[i];
    int pos = offs[d] + atomicAdd(&cur[d], 1);
    csrc[pos] = src[i];
  }
}

// ---------------- fp32 -> bf16 conversion ----------------
__global__ void k_f2b(const float* __restrict__ in, u16* __restrict__ out, int n){
  int i = (blockIdx.x * 256 + threadIdx.x) * 4;
  if (i >= n) return;
  float4 v = *reinterpret_cast<const float4*>(in + i);
  ushort4 o; o.x = f2b(v.x); o.y = f2b(v.y); o.z = f2b(v.z); o.w = f2b(v.w);
  *reinterpret_cast<ushort4*>(out + i) = o;
}

// W [K][256] fp32 -> transposed concat Wtc [256][2K] bf16: cols 0..K-1 = hi, K..2K-1 = residual
__global__ void k_wsplit(const float* __restrict__ W, u16* __restrict__ Wtc, int K){
  int e = blockIdx.x * 256 + threadIdx.x;
  if (e >= K * 256) return;
  int k = e >> 8, c = e & 255;
  float w = W[e];
  u16 hi = f2b(w);
  float lo = w - b2f(hi);
  Wtc[(size_t)c * 2 * K + k] = hi;
  Wtc[(size_t)c * 2 * K + K + k] = f2b(lo);
}

// ---------------- bf16 MFMA GEMM (m97 structure): C[MPAD][256] = Acat[MPAD][2K] @ Wtc^T ----
// Acat col k maps to A col (k & (K-1)); Wtc is [256][2K].
// Block: 256 thr / 4 waves; tile 64x256 (wave w: cols w*64..+64); BK=32.
template<int K>
__global__ __launch_bounds__(256) void k_gemm_bf(
    const u16* __restrict__ A, const u16* __restrict__ Wtc, u16* __restrict__ C)
{
  constexpr int K2 = 2 * K;
  __shared__ union {
    struct { u16 a[64 * 32]; u16 b[256 * 32]; } s;  // 4KB + 16KB
    u16 ct[64 * 256];                               // 32KB epilogue staging
  } L;
  int t = threadIdx.x;
  int wv = t >> 6, lane = t & 63;
  int row0 = blockIdx.x * 64;
  int lr = lane & 15, lk = lane >> 4;

  f32x4 acc[4][4];
  #pragma unroll
  for (int m = 0; m < 4; m++)
    #pragma unroll
    for (int n = 0; n < 4; n++) acc[m][n] = (f32x4){0.f, 0.f, 0.f, 0.f};

  // staging source bases (lane l stages 16B granule: row l>>2 of wave strip, colgroup l&3)
  const u16* asrc = A + (size_t)(row0 + wv * 16 + (lane >> 2)) * K + (lane & 3) * 8;
  u16* aldst = &L.s.a[wv * 512];
  const u16* bsrc0 = Wtc + (size_t)(wv * 64 + 0 * 16 + (lane >> 2)) * K2 + (lane & 3) * 8;
  const u16* bsrc1 = Wtc + (size_t)(wv * 64 + 1 * 16 + (lane >> 2)) * K2 + (lane & 3) * 8;
  const u16* bsrc2 = Wtc + (size_t)(wv * 64 + 2 * 16 + (lane >> 2)) * K2 + (lane & 3) * 8;
  const u16* bsrc3 = Wtc + (size_t)(wv * 64 + 3 * 16 + (lane >> 2)) * K2 + (lane & 3) * 8;
  u16* bldst0 = &L.s.b[wv * 2048 + 0 * 512];
  u16* bldst1 = &L.s.b[wv * 2048 + 1 * 512];
  u16* bldst2 = &L.s.b[wv * 2048 + 2 * 512];
  u16* bldst3 = &L.s.b[wv * 2048 + 3 * 512];

  for (int k0 = 0; k0 < K2; k0 += 32){
    int acol = k0 & (K - 1);
    gl_lds16(asrc + acol, aldst);
    gl_lds16(bsrc0 + k0, bldst0);
    gl_lds16(bsrc1 + k0, bldst1);
    gl_lds16(bsrc2 + k0, bldst2);
    gl_lds16(bsrc3 + k0, bldst3);
    __syncthreads();
    short8 af[4], bf[4];
    #pragma unroll
    for (int m = 0; m < 4; m++)
      af[m] = *reinterpret_cast<const short8*>(&L.s.a[(m * 16 + lr) * 32 + lk * 8]);
    #pragma unroll
    for (int n = 0; n < 4; n++)
      bf[n] = *reinterpret_cast<const short8*>(&L.s.b[(wv * 64 + n * 16 + lr) * 32 + lk * 8]);
    #pragma unroll
    for (int m = 0; m < 4; m++)
      #pragma unroll
      for (int n = 0; n < 4; n++)
        acc[m][n] = __builtin_amdgcn_mfma_f32_16x16x32_bf16(af[m], bf[n], acc[m][n], 0, 0, 0);
    __syncthreads();
  }

  // epilogue: acc -> bf16 LDS tile -> coalesced 16B stores
  int rg = lane >> 4;
  #pragma unroll
  for (int m = 0; m < 4; m++)
    #pragma unroll
    for (int n = 0; n < 4; n++)
      #pragma unroll
      for (int r = 0; r < 4; r++)
        L.ct[(m * 16 + rg * 4 + r) * 256 + wv * 64 + n * 16 + lr] = f2b(acc[m][n][r]);
  __syncthreads();
  #pragma unroll
  for (int l = 0; l < 8; l++){
    int idx = t + l * 256;            // 0..2047
    int row = idx >> 5, colg = idx & 31;
    short8 v = *reinterpret_cast<const short8*>(&L.ct[row * 256 + colg * 8]);
    *reinterpret_cast<short8*>(C + (size_t)(row0 + row) * 256 + colg * 8) = v;
  }
}

// ---------------- attention scores from bf16 feat ----------------
__global__ __launch_bounds__(256) void k_scores_bf(const u16* __restrict__ feat,
    const float* __restrict__ attn_l, const float* __restrict__ attn_r,
    float* __restrict__ el, float* __restrict__ er)
{
  int wv = threadIdx.x >> 6, lane = threadIdx.x & 63;
  int n = blockIdx.x * 4 + wv;
  if (n >= NN) return;
  ushort4 f = *reinterpret_cast<const ushort4*>(feat + (size_t)n * FH + lane * 4);
  float4 al = *reinterpret_cast<const float4*>(&attn_l[lane * 4]);
  float4 ar = *reinterpret_cast<const float4*>(&attn_r[lane * 4]);
  float fx = b2f(f.x), fy = b2f(f.y), fz = b2f(f.z), fw = b2f(f.w);
  float pl = fx * al.x + fy * al.y + fz * al.z + fw * al.w;
  float pr = fx * ar.x + fy * ar.y + fz * ar.z + fw * ar.w;
  #pragma unroll
  for (int d = 1; d < 16; d <<= 1){
    pl += __shfl_xor(pl, d);
    pr += __shfl_xor(pr, d);
  }
  if ((lane & 15) == 0){
    el[n * 4 + (lane >> 4)] = pl;
    er[n * 4 + (lane >> 4)] = pr;
  }
}

// ---------------- fused single-pass online-softmax aggregation ----------------
template<int LAYER>
__global__ __launch_bounds__(256) void k_agg(const u16* __restrict__ feat,
    const float* __restrict__ el, const float* __restrict__ er,
    const int* __restrict__ offs, const int* __restrict__ csrc,
    const float* __restrict__ bias, void* __restrict__ outv)
{
  __shared__ volatile float s_ex[4][64][4];
  __shared__ volatile int   s_src[4][64];
  int wv = threadIdx.x >> 6, lane = threadIdx.x & 63;
  int n = blockIdx.x * 4 + wv;
  if (n >= NN) return;
  int e0 = offs[n];
  int deg = offs[n + 1] - e0;
  int h = lane >> 4;
  float4 er4 = *reinterpret_cast<const float4*>(&er[n * 4]);

  float m_own = -1e30f, srun = 0.f;
  float a0 = 0.f, a1 = 0.f, a2 = 0.f, a3 = 0.f;

  for (int base = 0; base < deg; base += 64){
    int cnt = min(64, deg - base);
    float e0h, e1h, e2h, e3h;
    if (lane < cnt){
      int sj = csrc[e0 + base + lane];
      float4 l4 = *reinterpret_cast<const float4*>(&el[sj * 4]);
      e0h = leaky(l4.x + er4.x); e1h = leaky(l4.y + er4.y);
      e2h = leaky(l4.z + er4.z); e3h = leaky(l4.w + er4.w);
      s_src[wv][lane] = sj;
    } else {
      e0h = e1h = e2h = e3h = -1e30f;
    }
    // chunk max per head (all lanes get all 4)
    float c0 = e0h, c1 = e1h, c2 = e2h, c3 = e3h;
    #pragma unroll
    for (int d = 1; d < 64; d <<= 1){
      c0 = fmaxf(c0, __shfl_xor(c0, d)); c1 = fmaxf(c1, __shfl_xor(c1, d));
      c2 = fmaxf(c2, __shfl_xor(c2, d)); c3 = fmaxf(c3, __shfl_xor(c3, d));
    }
    // new running max per head (wave-uniform): old m of head hh lives in lanes hh*16..
    float nm0 = fmaxf(__shfl(m_own,  0), c0);
    float nm1 = fmaxf(__shfl(m_own, 16), c1);
    float nm2 = fmaxf(__shfl(m_own, 32), c2);
    float nm3 = fmaxf(__shfl(m_own, 48), c3);
    float ex0 = __expf(e0h - nm0), ex1 = __expf(e1h - nm1);
    float ex2 = __expf(e2h - nm2), ex3 = __expf(e3h - nm3);
    s_ex[wv][lane][0] = ex0; s_ex[wv][lane][1] = ex1;
    s_ex[wv][lane][2] = ex2; s_ex[wv][lane][3] = ex3;
    // chunk sum per head
    float t0 = ex0, t1 = ex1, t2 = ex2, t3 = ex3;
    #pragma unroll
    for (int d = 1; d < 64; d <<= 1){
      t0 += __shfl_xor(t0, d); t1 += __shfl_xor(t1, d);
      t2 += __shfl_xor(t2, d); t3 += __shfl_xor(t3, d);
    }
    float nm_own = (h == 0) ? nm0 : (h == 1) ? nm1 : (h == 2) ? nm2 : nm3;
    float sc_own = (h == 0) ? t0  : (h == 1) ? t1  : (h == 2) ? t2  : t3;
    float f = __expf(m_own - nm_own);
    srun = srun * f + sc_own;
    a0 *= f; a1 *= f; a2 *= f; a3 *= f;
    m_own = nm_own;
    // weighted feature accumulation for this chunk
    #pragma unroll 2
    for (int jj = 0; jj < cnt; jj++){
      int sj = s_src[wv][jj];
      float w = s_ex[wv][jj][h];
      ushort4 fv = *reinterpret_cast<const ushort4*>(feat + (size_t)sj * FH + lane * 4);
      a0 = fmaf(w, b2f(fv.x), a0);
      a1 = fmaf(w, b2f(fv.y), a1);
      a2 = fmaf(w, b2f(fv.z), a2);
      a3 = fmaf(w, b2f(fv.w), a3);
    }
  }

  float inv = (deg > 0) ? 1.f / srun : 0.f;
  float4 bv = *reinterpret_cast<const float4*>(&bias[lane * 4]);
  a0 = elu1(a0 * inv + bv.x); a1 = elu1(a1 * inv + bv.y);
  a2 = elu1(a2 * inv + bv.z); a3 = elu1(a3 * inv + bv.w);

  if (LAYER == 1){
    u16* out = (u16*)outv;
    ushort4 o; o.x = f2b(a0); o.y = f2b(a1); o.z = f2b(a2); o.w = f2b(a3);
    *reinterpret_cast<ushort4*>(out + (size_t)n * FH + lane * 4) = o;
  } else {
    float* out = (float*)outv;
    a0 += __shfl_xor(a0, 16); a0 += __shfl_xor(a0, 32);
    a1 += __shfl_xor(a1, 16); a1 += __shfl_xor(a1, 32);
    a2 += __shfl_xor(a2, 16); a2 += __shfl_xor(a2, 32);
    a3 += __shfl_xor(a3, 16); a3 += __shfl_xor(a3, 32);
    if (lane < 16){
      float4 o = make_float4(a0 * 0.25f, a1 * 0.25f, a2 * 0.25f, a3 * 0.25f);
      *reinterpret_cast<float4*>(out + (size_t)n * HID + lane * 4) = o;
    }
  }
}

// ---------------- graph sum-pooling (graph_ids sorted) ----------------
__global__ __launch_bounds__(256) void k_pool(const float* __restrict__ h2,
    const int* __restrict__ gid, float* __restrict__ pooled)
{
  int wv = threadIdx.x >> 6, lane = threadIdx.x & 63;
  int base = blockIdx.x * 1024;
  int curg = -1; float acc = 0.f;
  for (int i = wv; i < 1024; i += 4){
    int nn = base + i;
    if (nn >= NN) break;
    int g = gid[nn];
    if (g != curg){
      if (curg >= 0) atomicAdd(&pooled[curg * HID + lane], acc);
      curg = g; acc = 0.f;
    }
    acc += h2[(size_t)nn * HID + lane];
  }
  if (curg >= 0) atomicAdd(&pooled[curg * HID + lane], acc);
}

// ---------------- final FC ----------------
__global__ void k_fc(const float* __restrict__ pooled, const float* __restrict__ fcW,
                     const float* __restrict__ fcb, float* __restrict__ out)
{
  int t = threadIdx.x;
  if (t >= NG * NOUT) return;
  int g = t / NOUT, o = t % NOUT;
  float s = fcb[o];
  for (int d = 0; d < HID; d++) s = fmaf(pooled[g * HID + d], fcW[d * NOUT + o], s);
  out[t] = s;
}

static inline size_t align_up(size_t x){ return (x + 255) & ~(size_t)255; }

extern "C" void kernel_launch(void* const* d_in, const int* in_sizes, int n_in,
                              void* d_out, int out_size, void* d_ws, size_t ws_size,
                              hipStream_t stream) {
  const float* x    = (const float*)d_in[0];
  const int*   src  = (const int*)d_in[1];
  const int*   dst  = (const int*)d_in[2];
  const int*   gid  = (const int*)d_in[3];
  const float* W1   = (const float*)d_in[4];
  const float* al1  = (const float*)d_in[5];
  const float* ar1  = (const float*)d_in[6];
  const float* b1   = (const float*)d_in[7];
  const float* W2   = (const float*)d_in[8];
  const float* al2  = (const float*)d_in[9];
  const float* ar2  = (const float*)d_in[10];
  const float* b2   = (const float*)d_in[11];
  const float* fcW  = (const float*)d_in[12];
  const float* fcb  = (const float*)d_in[13];
  float* out = (float*)d_out;

  char* p = (char*)d_ws;
  int* cnt  = (int*)p; p += align_up((size_t)NN * 4);
  int* cur  = (int*)p; p += align_up((size_t)NN * 4);
  int* offs = (int*)p; p += align_up((size_t)(NN + 1) * 4);
  int* csrc = (int*)p; p += align_up((size_t)NE * 4);
  u16* xh    = (u16*)p; p += align_up((size_t)MPAD * FIN * 2);
  u16* feath = (u16*)p; p += align_up((size_t)MPAD * FH * 2);
  u16* h1h   = (u16*)p; p += align_up((size_t)MPAD * FH * 2);
  float* elb = (float*)p; p += align_up((size_t)NN * NH * 4);
  float* erb = (float*)p; p += align_up((size_t)NN * NH * 4);
  float* h2  = (float*)p; p += align_up((size_t)NN * HID * 4);
  float* pooled = (float*)p; p += align_up((size_t)NG * HID * 4);
  u16* Wtc1 = (u16*)p; p += align_up((size_t)FIN * FH * 2 * 2);
  u16* Wtc2 = (u16*)p; p += align_up((size_t)FH * FH * 2 * 2);

  hipMemsetAsync(cnt, 0, (size_t)((char*)offs - (char*)cnt), stream);

  const int EB = (NE + 255) / 256;      // 3125
  const int NB4 = (NN + 3) / 4;         // 12500
  const int GB = MPAD / 64;             // 782

  k_hist<<<EB, 256, 0, stream>>>(dst, cnt);
  k_scan<<<1, 1024, 0, stream>>>(cnt, offs);
  k_scatter<<<EB, 256, 0, stream>>>(src, dst, offs, cur, csrc);

  k_f2b<<<(NN * FIN / 4 + 255) / 256, 256, 0, stream>>>(x, xh, NN * FIN);
  k_wsplit<<<(FIN * FH + 255) / 256, 256, 0, stream>>>(W1, Wtc1, FIN);
  k_wsplit<<<(FH * FH + 255) / 256, 256, 0, stream>>>(W2, Wtc2, FH);

  // layer 1
  k_gemm_bf<FIN><<<GB, 256, 0, stream>>>(xh, Wtc1, feath);
  k_scores_bf<<<NB4, 256, 0, stream>>>(feath, al1, ar1, elb, erb);
  k_agg<1><<<NB4, 256, 0, stream>>>(feath, elb, erb, offs, csrc, b1, h1h);

  // layer 2
  k_gemm_bf<FH><<<GB, 256, 0, stream>>>(h1h, Wtc2, feath);
  k_scores_bf<<<NB4, 256, 0, stream>>>(feath, al2, ar2, elb, erb);
  k_agg<2><<<NB4, 256, 0, stream>>>(feath, elb, erb, offs, csrc, b2, h2);

  // pooling + FC
  hipMemsetAsync(pooled, 0, (size_t)NG * HID * 4, stream);
  k_pool<<<(NN + 1023) / 1024, 256, 0, stream>>>(h2, gid, pooled);
  k_fc<<<1, 640, 0, stream>>>(pooled, fcW, fcb, out);
}

// Round 4
// 440.892 us; speedup vs baseline: 1.6917x; 1.2357x over previous
//
#include <hip/hip_runtime.h>
#include <math.h>

#define NN 50000
#define MPAD 50048   // 782 * 64
#define NE 800000
#define NG 64
#define FIN 128
#define FH 256      // heads * HID = 4*64, both layers
#define HID 64
#define NH 4
#define NOUT 10
#define NEG_SLOPE 0.2f

typedef unsigned short u16;
typedef __attribute__((ext_vector_type(8))) short short8;
typedef __attribute__((ext_vector_type(4))) float f32x4;

static __device__ __forceinline__ float leaky(float x){ return x > 0.f ? x : NEG_SLOPE * x; }
static __device__ __forceinline__ float elu1(float x){ return x > 0.f ? x : (__expf(x) - 1.f); }
static __device__ __forceinline__ float b2f(u16 u){
  union { unsigned int i; float f; } v; v.i = ((unsigned)u) << 16; return v.f;
}
static __device__ __forceinline__ u16 f2b(float f){
  union { float f; unsigned int i; } v; v.f = f;
  unsigned r = v.i + 0x7FFFu + ((v.i >> 16) & 1u);
  return (u16)(r >> 16);
}

static __device__ __forceinline__ void gl_lds16(const u16* g, u16* l){
  __builtin_amdgcn_global_load_lds(
      (const __attribute__((address_space(1))) void*)g,
      (__attribute__((address_space(3))) void*)l, 16, 0, 0);
}

// ---------------- CSR build ----------------
__global__ void k_hist(const int* __restrict__ dst, int* __restrict__ cnt){
  int i = blockIdx.x * blockDim.x + threadIdx.x;
  if (i < NE) atomicAdd(&cnt[dst[i]], 1);
}

__global__ void k_scan(const int* __restrict__ cnt, int* __restrict__ offs){
  __shared__ int sums[1024];
  int t = threadIdx.x;
  const int CH = (NN + 1023) / 1024;
  int base = t * CH;
  int s = 0;
  for (int j = 0; j < CH; j++){
    int idx = base + j;
    if (idx < NN) s += cnt[idx];
  }
  sums[t] = s;
  __syncthreads();
  for (int d = 1; d < 1024; d <<= 1){
    int v = (t >= d) ? sums[t - d] : 0;
    __syncthreads();
    sums[t] += v;
    __syncthreads();
  }
  int run = (t == 0) ? 0 : sums[t - 1];
  for (int j = 0; j < CH; j++){
    int idx = base + j;
    if (idx < NN){ offs[idx] = run; run += cnt[idx]; }
  }
  if (t == 0) offs[NN] = NE;
}

__global__ void k_scatter(const int* __restrict__ src, const int* __restrict__ dst,
                          const int* __restrict__ offs, int* __restrict__ cur,
                          int* __restrict__ csrc){
  int i = blockIdx.x * blockDim.x + threadIdx.x;
  if (i < NE){
    int d = dst[i];
    int pos = offs[d] + atomicAdd(&cur[d], 1);
    csrc[pos] = src[i];
  }
}

// ---------------- fp32 -> bf16 conversion ----------------
__global__ void k_f2b(const float* __restrict__ in, u16* __restrict__ out, int n){
  int i = (blockIdx.x * 256 + threadIdx.x) * 4;
  if (i >= n) return;
  float4 v = *reinterpret_cast<const float4*>(in + i);
  ushort4 o; o.x = f2b(v.x); o.y = f2b(v.y); o.z = f2b(v.z); o.w = f2b(v.w);
  *reinterpret_cast<ushort4*>(out + i) = o;
}

// W [K][256] fp32 -> transposed concat Wtc [256][2K] bf16: cols 0..K-1 = hi, K..2K-1 = residual
__global__ void k_wsplit(const float* __restrict__ W, u16* __restrict__ Wtc, int K){
  int e = blockIdx.x * 256 + threadIdx.x;
  if (e >= K * 256) return;
  int k = e >> 8, c = e & 255;
  float w = W[e];
  u16 hi = f2b(w);
  float lo = w - b2f(hi);
  Wtc[(size_t)c * 2 * K + k] = hi;
  Wtc[(size_t)c * 2 * K + K + k] = f2b(lo);
}

// ---------------- bf16 MFMA GEMM (m97 structure): C[MPAD][256] = Acat[MPAD][2K] @ Wtc^T ----
template<int K>
__global__ __launch_bounds__(256) void k_gemm_bf(
    const u16* __restrict__ A, const u16* __restrict__ Wtc, u16* __restrict__ C)
{
  constexpr int K2 = 2 * K;
  __shared__ union {
    struct { u16 a[64 * 32]; u16 b[256 * 32]; } s;  // 4KB + 16KB
    u16 ct[64 * 256];                               // 32KB epilogue staging
  } L;
  int t = threadIdx.x;
  int wv = t >> 6, lane = t & 63;
  int row0 = blockIdx.x * 64;
  int lr = lane & 15, lk = lane >> 4;

  f32x4 acc[4][4];
  #pragma unroll
  for (int m = 0; m < 4; m++)
    #pragma unroll
    for (int n = 0; n < 4; n++) acc[m][n] = (f32x4){0.f, 0.f, 0.f, 0.f};

  const u16* asrc = A + (size_t)(row0 + wv * 16 + (lane >> 2)) * K + (lane & 3) * 8;
  u16* aldst = &L.s.a[wv * 512];
  const u16* bsrc0 = Wtc + (size_t)(wv * 64 + 0 * 16 + (lane >> 2)) * K2 + (lane & 3) * 8;
  const u16* bsrc1 = Wtc + (size_t)(wv * 64 + 1 * 16 + (lane >> 2)) * K2 + (lane & 3) * 8;
  const u16* bsrc2 = Wtc + (size_t)(wv * 64 + 2 * 16 + (lane >> 2)) * K2 + (lane & 3) * 8;
  const u16* bsrc3 = Wtc + (size_t)(wv * 64 + 3 * 16 + (lane >> 2)) * K2 + (lane & 3) * 8;
  u16* bldst0 = &L.s.b[wv * 2048 + 0 * 512];
  u16* bldst1 = &L.s.b[wv * 2048 + 1 * 512];
  u16* bldst2 = &L.s.b[wv * 2048 + 2 * 512];
  u16* bldst3 = &L.s.b[wv * 2048 + 3 * 512];

  for (int k0 = 0; k0 < K2; k0 += 32){
    int acol = k0 & (K - 1);
    gl_lds16(asrc + acol, aldst);
    gl_lds16(bsrc0 + k0, bldst0);
    gl_lds16(bsrc1 + k0, bldst1);
    gl_lds16(bsrc2 + k0, bldst2);
    gl_lds16(bsrc3 + k0, bldst3);
    __syncthreads();
    short8 af[4], bf[4];
    #pragma unroll
    for (int m = 0; m < 4; m++)
      af[m] = *reinterpret_cast<const short8*>(&L.s.a[(m * 16 + lr) * 32 + lk * 8]);
    #pragma unroll
    for (int n = 0; n < 4; n++)
      bf[n] = *reinterpret_cast<const short8*>(&L.s.b[(wv * 64 + n * 16 + lr) * 32 + lk * 8]);
    #pragma unroll
    for (int m = 0; m < 4; m++)
      #pragma unroll
      for (int n = 0; n < 4; n++)
        acc[m][n] = __builtin_amdgcn_mfma_f32_16x16x32_bf16(af[m], bf[n], acc[m][n], 0, 0, 0);
    __syncthreads();
  }

  int rg = lane >> 4;
  #pragma unroll
  for (int m = 0; m < 4; m++)
    #pragma unroll
    for (int n = 0; n < 4; n++)
      #pragma unroll
      for (int r = 0; r < 4; r++)
        L.ct[(m * 16 + rg * 4 + r) * 256 + wv * 64 + n * 16 + lr] = f2b(acc[m][n][r]);
  __syncthreads();
  #pragma unroll
  for (int l = 0; l < 8; l++){
    int idx = t + l * 256;
    int row = idx >> 5, colg = idx & 31;
    short8 v = *reinterpret_cast<const short8*>(&L.ct[row * 256 + colg * 8]);
    *reinterpret_cast<short8*>(C + (size_t)(row0 + row) * 256 + colg * 8) = v;
  }
}

// ---------------- attention scores from bf16 feat ----------------
__global__ __launch_bounds__(256) void k_scores_bf(const u16* __restrict__ feat,
    const float* __restrict__ attn_l, const float* __restrict__ attn_r,
    float* __restrict__ el, float* __restrict__ er)
{
  int wv = threadIdx.x >> 6, lane = threadIdx.x & 63;
  int n = blockIdx.x * 4 + wv;
  if (n >= NN) return;
  ushort4 f = *reinterpret_cast<const ushort4*>(feat + (size_t)n * FH + lane * 4);
  float4 al = *reinterpret_cast<const float4*>(&attn_l[lane * 4]);
  float4 ar = *reinterpret_cast<const float4*>(&attn_r[lane * 4]);
  float fx = b2f(f.x), fy = b2f(f.y), fz = b2f(f.z), fw = b2f(f.w);
  float pl = fx * al.x + fy * al.y + fz * al.z + fw * al.w;
  float pr = fx * ar.x + fy * ar.y + fz * ar.z + fw * ar.w;
  #pragma unroll
  for (int d = 1; d < 16; d <<= 1){
    pl += __shfl_xor(pl, d);
    pr += __shfl_xor(pr, d);
  }
  if ((lane & 15) == 0){
    el[n * 4 + (lane >> 4)] = pl;
    er[n * 4 + (lane >> 4)] = pr;
  }
}

// ---------------- fused single-pass online-softmax aggregation ----------------
template<int LAYER>
__global__ __launch_bounds__(256) void k_agg(const u16* __restrict__ feat,
    const float* __restrict__ el, const float* __restrict__ er,
    const int* __restrict__ offs, const int* __restrict__ csrc,
    const float* __restrict__ bias, void* __restrict__ outv)
{
  __shared__ volatile float s_ex[4][64][4];
  __shared__ volatile int   s_src[4][64];
  int wv = threadIdx.x >> 6, lane = threadIdx.x & 63;
  int n = blockIdx.x * 4 + wv;
  if (n >= NN) return;
  int e0 = offs[n];
  int deg = offs[n + 1] - e0;
  int h = lane >> 4;
  float4 er4 = *reinterpret_cast<const float4*>(&er[n * 4]);

  float m_own = -1e30f, srun = 0.f;
  float a0 = 0.f, a1 = 0.f, a2 = 0.f, a3 = 0.f;

  for (int base = 0; base < deg; base += 64){
    int cnt = min(64, deg - base);
    float e0h, e1h, e2h, e3h;
    if (lane < cnt){
      int sj = csrc[e0 + base + lane];
      float4 l4 = *reinterpret_cast<const float4*>(&el[sj * 4]);
      e0h = leaky(l4.x + er4.x); e1h = leaky(l4.y + er4.y);
      e2h = leaky(l4.z + er4.z); e3h = leaky(l4.w + er4.w);
      s_src[wv][lane] = sj;
    } else {
      e0h = e1h = e2h = e3h = -1e30f;
    }
    float c0 = e0h, c1 = e1h, c2 = e2h, c3 = e3h;
    #pragma unroll
    for (int d = 1; d < 64; d <<= 1){
      c0 = fmaxf(c0, __shfl_xor(c0, d)); c1 = fmaxf(c1, __shfl_xor(c1, d));
      c2 = fmaxf(c2, __shfl_xor(c2, d)); c3 = fmaxf(c3, __shfl_xor(c3, d));
    }
    float nm0 = fmaxf(__shfl(m_own,  0), c0);
    float nm1 = fmaxf(__shfl(m_own, 16), c1);
    float nm2 = fmaxf(__shfl(m_own, 32), c2);
    float nm3 = fmaxf(__shfl(m_own, 48), c3);
    float ex0 = __expf(e0h - nm0), ex1 = __expf(e1h - nm1);
    float ex2 = __expf(e2h - nm2), ex3 = __expf(e3h - nm3);
    s_ex[wv][lane][0] = ex0; s_ex[wv][lane][1] = ex1;
    s_ex[wv][lane][2] = ex2; s_ex[wv][lane][3] = ex3;
    float t0 = ex0, t1 = ex1, t2 = ex2, t3 = ex3;
    #pragma unroll
    for (int d = 1; d < 64; d <<= 1){
      t0 += __shfl_xor(t0, d); t1 += __shfl_xor(t1, d);
      t2 += __shfl_xor(t2, d); t3 += __shfl_xor(t3, d);
    }
    float nm_own = (h == 0) ? nm0 : (h == 1) ? nm1 : (h == 2) ? nm2 : nm3;
    float sc_own = (h == 0) ? t0  : (h == 1) ? t1  : (h == 2) ? t2  : t3;
    float f = __expf(m_own - nm_own);
    srun = srun * f + sc_own;
    a0 *= f; a1 *= f; a2 *= f; a3 *= f;
    m_own = nm_own;
    #pragma unroll 2
    for (int jj = 0; jj < cnt; jj++){
      int sj = s_src[wv][jj];
      float w = s_ex[wv][jj][h];
      ushort4 fv = *reinterpret_cast<const ushort4*>(feat + (size_t)sj * FH + lane * 4);
      a0 = fmaf(w, b2f(fv.x), a0);
      a1 = fmaf(w, b2f(fv.y), a1);
      a2 = fmaf(w, b2f(fv.z), a2);
      a3 = fmaf(w, b2f(fv.w), a3);
    }
  }

  float inv = (deg > 0) ? 1.f / srun : 0.f;
  float4 bv = *reinterpret_cast<const float4*>(&bias[lane * 4]);
  a0 = elu1(a0 * inv + bv.x); a1 = elu1(a1 * inv + bv.y);
  a2 = elu1(a2 * inv + bv.z); a3 = elu1(a3 * inv + bv.w);

  if (LAYER == 1){
    u16* out = (u16*)outv;
    ushort4 o; o.x = f2b(a0); o.y = f2b(a1); o.z = f2b(a2); o.w = f2b(a3);
    *reinterpret_cast<ushort4*>(out + (size_t)n * FH + lane * 4) = o;
  } else {
    float* out = (float*)outv;
    a0 += __shfl_xor(a0, 16); a0 += __shfl_xor(a0, 32);
    a1 += __shfl_xor(a1, 16); a1 += __shfl_xor(a1, 32);
    a2 += __shfl_xor(a2, 16); a2 += __shfl_xor(a2, 32);
    a3 += __shfl_xor(a3, 16); a3 += __shfl_xor(a3, 32);
    if (lane < 16){
      float4 o = make_float4(a0 * 0.25f, a1 * 0.25f, a2 * 0.25f, a3 * 0.25f);
      *reinterpret_cast<float4*>(out + (size_t)n * HID + lane * 4) = o;
    }
  }
}

// ---------------- graph sum-pooling: 1 wave per 64-node chunk ----------------
// Per iteration a wave covers 4 rows (lane>>4 -> row, lane&15 -> float4 cols).
__global__ __launch_bounds__(256) void k_pool(const float* __restrict__ h2,
    const int* __restrict__ gid, float* __restrict__ pooled)
{
  int wv = threadIdx.x >> 6, lane = threadIdx.x & 63;
  int w = blockIdx.x * 4 + wv;
  int base = w * 64;
  if (base >= NN) return;
  int grp = lane >> 4, c4 = (lane & 15) * 4;
  int curg = -1;
  float4 acc = make_float4(0.f, 0.f, 0.f, 0.f);
  #pragma unroll 4
  for (int it = 0; it < 16; it++){
    int row = base + it * 4 + grp;
    if (row >= NN) break;
    int g = gid[row];
    if (g != curg){
      if (curg >= 0){
        atomicAdd(&pooled[curg * HID + c4 + 0], acc.x);
        atomicAdd(&pooled[curg * HID + c4 + 1], acc.y);
        atomicAdd(&pooled[curg * HID + c4 + 2], acc.z);
        atomicAdd(&pooled[curg * HID + c4 + 3], acc.w);
      }
      curg = g; acc = make_float4(0.f, 0.f, 0.f, 0.f);
    }
    float4 v = *reinterpret_cast<const float4*>(&h2[(size_t)row * HID + c4]);
    acc.x += v.x; acc.y += v.y; acc.z += v.z; acc.w += v.w;
  }
  if (curg >= 0){
    atomicAdd(&pooled[curg * HID + c4 + 0], acc.x);
    atomicAdd(&pooled[curg * HID + c4 + 1], acc.y);
    atomicAdd(&pooled[curg * HID + c4 + 2], acc.z);
    atomicAdd(&pooled[curg * HID + c4 + 3], acc.w);
  }
}

// ---------------- final FC ----------------
__global__ void k_fc(const float* __restrict__ pooled, const float* __restrict__ fcW,
                     const float* __restrict__ fcb, float* __restrict__ out)
{
  int t = threadIdx.x;
  if (t >= NG * NOUT) return;
  int g = t / NOUT, o = t % NOUT;
  float s = fcb[o];
  for (int d = 0; d < HID; d++) s = fmaf(pooled[g * HID + d], fcW[d * NOUT + o], s);
  out[t] = s;
}

static inline size_t align_up(size_t x){ return (x + 255) & ~(size_t)255; }

extern "C" void kernel_launch(void* const* d_in, const int* in_sizes, int n_in,
                              void* d_out, int out_size, void* d_ws, size_t ws_size,
                              hipStream_t stream) {
  const float* x    = (const float*)d_in[0];
  const int*   src  = (const int*)d_in[1];
  const int*   dst  = (const int*)d_in[2];
  const int*   gid  = (const int*)d_in[3];
  const float* W1   = (const float*)d_in[4];
  const float* al1  = (const float*)d_in[5];
  const float* ar1  = (const float*)d_in[6];
  const float* b1   = (const float*)d_in[7];
  const float* W2   = (const float*)d_in[8];
  const float* al2  = (const float*)d_in[9];
  const float* ar2  = (const float*)d_in[10];
  const float* b2   = (const float*)d_in[11];
  const float* fcW  = (const float*)d_in[12];
  const float* fcb  = (const float*)d_in[13];
  float* out = (float*)d_out;

  char* p = (char*)d_ws;
  int* cnt  = (int*)p; p += align_up((size_t)NN * 4);
  int* cur  = (int*)p; p += align_up((size_t)NN * 4);
  int* offs = (int*)p; p += align_up((size_t)(NN + 1) * 4);
  int* csrc = (int*)p; p += align_up((size_t)NE * 4);
  u16* xh    = (u16*)p; p += align_up((size_t)MPAD * FIN * 2);
  u16* feath = (u16*)p; p += align_up((size_t)MPAD * FH * 2);
  u16* h1h   = (u16*)p; p += align_up((size_t)MPAD * FH * 2);
  float* elb = (float*)p; p += align_up((size_t)NN * NH * 4);
  float* erb = (float*)p; p += align_up((size_t)NN * NH * 4);
  float* h2  = (float*)p; p += align_up((size_t)NN * HID * 4);
  float* pooled = (float*)p; p += align_up((size_t)NG * HID * 4);
  u16* Wtc1 = (u16*)p; p += align_up((size_t)FIN * FH * 2 * 2);
  u16* Wtc2 = (u16*)p; p += align_up((size_t)FH * FH * 2 * 2);

  hipMemsetAsync(cnt, 0, (size_t)((char*)offs - (char*)cnt), stream);

  const int EB = (NE + 255) / 256;      // 3125
  const int NB4 = (NN + 3) / 4;         // 12500
  const int GB = MPAD / 64;             // 782

  k_hist<<<EB, 256, 0, stream>>>(dst, cnt);
  k_scan<<<1, 1024, 0, stream>>>(cnt, offs);
  k_scatter<<<EB, 256, 0, stream>>>(src, dst, offs, cur, csrc);

  k_f2b<<<(NN * FIN / 4 + 255) / 256, 256, 0, stream>>>(x, xh, NN * FIN);
  k_wsplit<<<(FIN * FH + 255) / 256, 256, 0, stream>>>(W1, Wtc1, FIN);
  k_wsplit<<<(FH * FH + 255) / 256, 256, 0, stream>>>(W2, Wtc2, FH);

  // layer 1
  k_gemm_bf<FIN><<<GB, 256, 0, stream>>>(xh, Wtc1, feath);
  k_scores_bf<<<NB4, 256, 0, stream>>>(feath, al1, ar1, elb, erb);
  k_agg<1><<<NB4, 256, 0, stream>>>(feath, elb, erb, offs, csrc, b1, h1h);

  // layer 2
  k_gemm_bf<FH><<<GB, 256, 0, stream>>>(h1h, Wtc2, feath);
  k_scores_bf<<<NB4, 256, 0, stream>>>(feath, al2, ar2, elb, erb);
  k_agg<2><<<NB4, 256, 0, stream>>>(feath, elb, erb, offs, csrc, b2, h2);

  // pooling + FC
  hipMemsetAsync(pooled, 0, (size_t)NG * HID * 4, stream);
  k_pool<<<(NN + 255) / 256, 256, 0, stream>>>(h2, gid, pooled);
  k_fc<<<1, 640, 0, stream>>>(pooled, fcW, fcb, out);
}

// Round 5
// 349.738 us; speedup vs baseline: 2.1327x; 1.2606x over previous
//
#include <hip/hip_runtime.h>
#include <math.h>

#define NN 50000
#define MPAD 50048   // 782 * 64
#define NE 800000
#define NG 64
#define FIN 128
#define FH 256      // heads * HID = 4*64, both layers
#define HID 64
#define NH 4
#define NOUT 10
#define NEG_SLOPE 0.2f
#define NSB ((NN + 1023) / 1024)   // 49 scan blocks

typedef unsigned short u16;
typedef __attribute__((ext_vector_type(8))) short short8;
typedef __attribute__((ext_vector_type(4))) float f32x4;

static __device__ __forceinline__ float leaky(float x){ return x > 0.f ? x : NEG_SLOPE * x; }
static __device__ __forceinline__ float elu1(float x){ return x > 0.f ? x : (__expf(x) - 1.f); }
static __device__ __forceinline__ float b2f(u16 u){
  union { unsigned int i; float f; } v; v.i = ((unsigned)u) << 16; return v.f;
}
static __device__ __forceinline__ u16 f2b(float f){
  union { float f; unsigned int i; } v; v.f = f;
  unsigned r = v.i + 0x7FFFu + ((v.i >> 16) & 1u);
  return (u16)(r >> 16);
}

static __device__ __forceinline__ void gl_lds16(const u16* g, u16* l){
  __builtin_amdgcn_global_load_lds(
      (const __attribute__((address_space(1))) void*)g,
      (__attribute__((address_space(3))) void*)l, 16, 0, 0);
}

// ---------------- CSR build ----------------
__global__ void k_hist(const int* __restrict__ dst, int* __restrict__ cnt){
  int i = blockIdx.x * blockDim.x + threadIdx.x;
  if (i < NE) atomicAdd(&cnt[dst[i]], 1);
}

// hierarchical scan, stage 1: per-1024-chunk exclusive prefix + block total
__global__ __launch_bounds__(256) void k_scan1(const int* __restrict__ cnt,
    int* __restrict__ offs, int* __restrict__ bsum)
{
  __shared__ int wsum[4];
  int t = threadIdx.x;
  int lane = t & 63, wv = t >> 6;
  int base = blockIdx.x * 1024 + t * 4;
  int4 v = make_int4(0, 0, 0, 0);
  if (base + 3 < NN) v = *reinterpret_cast<const int4*>(cnt + base);
  else {
    if (base + 0 < NN) v.x = cnt[base + 0];
    if (base + 1 < NN) v.y = cnt[base + 1];
    if (base + 2 < NN) v.z = cnt[base + 2];
  }
  int s = v.x + v.y + v.z + v.w;
  int incl = s;
  #pragma unroll
  for (int d = 1; d < 64; d <<= 1){
    int u = __shfl_up(incl, d);
    if (lane >= d) incl += u;
  }
  if (lane == 63) wsum[wv] = incl;
  __syncthreads();
  int woff = 0;
  #pragma unroll
  for (int i = 0; i < 4; i++) if (i < wv) woff += wsum[i];
  int texcl = woff + incl - s;
  int e0 = texcl, e1 = e0 + v.x, e2 = e1 + v.y, e3 = e2 + v.z;
  if (base + 3 < NN) *reinterpret_cast<int4*>(offs + base) = make_int4(e0, e1, e2, e3);
  else {
    if (base + 0 < NN) offs[base + 0] = e0;
    if (base + 1 < NN) offs[base + 1] = e1;
    if (base + 2 < NN) offs[base + 2] = e2;
  }
  if (t == 255) bsum[blockIdx.x] = woff + incl;
}

// stage 2: scan the 49 block totals (one wave)
__global__ void k_scan2(const int* __restrict__ bsum, int* __restrict__ bpre,
                        int* __restrict__ offs)
{
  int lane = threadIdx.x;
  int s = (lane < NSB) ? bsum[lane] : 0;
  int incl = s;
  #pragma unroll
  for (int d = 1; d < 64; d <<= 1){
    int u = __shfl_up(incl, d);
    if (lane >= d) incl += u;
  }
  if (lane < NSB) bpre[lane] = incl - s;
  if (lane == 0) offs[NN] = NE;
}

// stage 3: add block prefix
__global__ __launch_bounds__(256) void k_scan3(int* __restrict__ offs,
    const int* __restrict__ bpre)
{
  int add = bpre[blockIdx.x];
  if (add == 0) return;
  int base = blockIdx.x * 1024 + threadIdx.x * 4;
  if (base + 3 < NN){
    int4 v = *reinterpret_cast<int4*>(offs + base);
    v.x += add; v.y += add; v.z += add; v.w += add;
    *reinterpret_cast<int4*>(offs + base) = v;
  } else {
    if (base + 0 < NN) offs[base + 0] += add;
    if (base + 1 < NN) offs[base + 1] += add;
    if (base + 2 < NN) offs[base + 2] += add;
  }
}

__global__ void k_scatter(const int* __restrict__ src, const int* __restrict__ dst,
                          const int* __restrict__ offs, int* __restrict__ cur,
                          int* __restrict__ csrc){
  int i = blockIdx.x * blockDim.x + threadIdx.x;
  if (i < NE){
    int d = dst[i];
    int pos = offs[d] + atomicAdd(&cur[d], 1);
    csrc[pos] = src[i];
  }
}

// ---------------- fp32 -> bf16 conversion ----------------
__global__ void k_f2b(const float* __restrict__ in, u16* __restrict__ out, int n){
  int i = (blockIdx.x * 256 + threadIdx.x) * 4;
  if (i >= n) return;
  float4 v = *reinterpret_cast<const float4*>(in + i);
  ushort4 o; o.x = f2b(v.x); o.y = f2b(v.y); o.z = f2b(v.z); o.w = f2b(v.w);
  *reinterpret_cast<ushort4*>(out + i) = o;
}

// W [K][256] fp32 -> transposed concat Wtc [256][2K] bf16: cols 0..K-1 = hi, K..2K-1 = residual
__global__ void k_wsplit(const float* __restrict__ W, u16* __restrict__ Wtc, int K){
  int e = blockIdx.x * 256 + threadIdx.x;
  if (e >= K * 256) return;
  int k = e >> 8, c = e & 255;
  float w = W[e];
  u16 hi = f2b(w);
  float lo = w - b2f(hi);
  Wtc[(size_t)c * 2 * K + k] = hi;
  Wtc[(size_t)c * 2 * K + K + k] = f2b(lo);
}

// ---------------- bf16 MFMA GEMM (m97 structure): C[MPAD][256] = Acat[MPAD][2K] @ Wtc^T ----
template<int K>
__global__ __launch_bounds__(256) void k_gemm_bf(
    const u16* __restrict__ A, const u16* __restrict__ Wtc, u16* __restrict__ C)
{
  constexpr int K2 = 2 * K;
  __shared__ union {
    struct { u16 a[64 * 32]; u16 b[256 * 32]; } s;  // 4KB + 16KB
    u16 ct[64 * 256];                               // 32KB epilogue staging
  } L;
  int t = threadIdx.x;
  int wv = t >> 6, lane = t & 63;
  int row0 = blockIdx.x * 64;
  int lr = lane & 15, lk = lane >> 4;

  f32x4 acc[4][4];
  #pragma unroll
  for (int m = 0; m < 4; m++)
    #pragma unroll
    for (int n = 0; n < 4; n++) acc[m][n] = (f32x4){0.f, 0.f, 0.f, 0.f};

  const u16* asrc = A + (size_t)(row0 + wv * 16 + (lane >> 2)) * K + (lane & 3) * 8;
  u16* aldst = &L.s.a[wv * 512];
  const u16* bsrc0 = Wtc + (size_t)(wv * 64 + 0 * 16 + (lane >> 2)) * K2 + (lane & 3) * 8;
  const u16* bsrc1 = Wtc + (size_t)(wv * 64 + 1 * 16 + (lane >> 2)) * K2 + (lane & 3) * 8;
  const u16* bsrc2 = Wtc + (size_t)(wv * 64 + 2 * 16 + (lane >> 2)) * K2 + (lane & 3) * 8;
  const u16* bsrc3 = Wtc + (size_t)(wv * 64 + 3 * 16 + (lane >> 2)) * K2 + (lane & 3) * 8;
  u16* bldst0 = &L.s.b[wv * 2048 + 0 * 512];
  u16* bldst1 = &L.s.b[wv * 2048 + 1 * 512];
  u16* bldst2 = &L.s.b[wv * 2048 + 2 * 512];
  u16* bldst3 = &L.s.b[wv * 2048 + 3 * 512];

  for (int k0 = 0; k0 < K2; k0 += 32){
    int acol = k0 & (K - 1);
    gl_lds16(asrc + acol, aldst);
    gl_lds16(bsrc0 + k0, bldst0);
    gl_lds16(bsrc1 + k0, bldst1);
    gl_lds16(bsrc2 + k0, bldst2);
    gl_lds16(bsrc3 + k0, bldst3);
    __syncthreads();
    short8 af[4], bf[4];
    #pragma unroll
    for (int m = 0; m < 4; m++)
      af[m] = *reinterpret_cast<const short8*>(&L.s.a[(m * 16 + lr) * 32 + lk * 8]);
    #pragma unroll
    for (int n = 0; n < 4; n++)
      bf[n] = *reinterpret_cast<const short8*>(&L.s.b[(wv * 64 + n * 16 + lr) * 32 + lk * 8]);
    #pragma unroll
    for (int m = 0; m < 4; m++)
      #pragma unroll
      for (int n = 0; n < 4; n++)
        acc[m][n] = __builtin_amdgcn_mfma_f32_16x16x32_bf16(af[m], bf[n], acc[m][n], 0, 0, 0);
    __syncthreads();
  }

  int rg = lane >> 4;
  #pragma unroll
  for (int m = 0; m < 4; m++)
    #pragma unroll
    for (int n = 0; n < 4; n++)
      #pragma unroll
      for (int r = 0; r < 4; r++)
        L.ct[(m * 16 + rg * 4 + r) * 256 + wv * 64 + n * 16 + lr] = f2b(acc[m][n][r]);
  __syncthreads();
  #pragma unroll
  for (int l = 0; l < 8; l++){
    int idx = t + l * 256;
    int row = idx >> 5, colg = idx & 31;
    short8 v = *reinterpret_cast<const short8*>(&L.ct[row * 256 + colg * 8]);
    *reinterpret_cast<short8*>(C + (size_t)(row0 + row) * 256 + colg * 8) = v;
  }
}

// ---------------- attention scores from bf16 feat ----------------
__global__ __launch_bounds__(256) void k_scores_bf(const u16* __restrict__ feat,
    const float* __restrict__ attn_l, const float* __restrict__ attn_r,
    float* __restrict__ el, float* __restrict__ er)
{
  int wv = threadIdx.x >> 6, lane = threadIdx.x & 63;
  int n = blockIdx.x * 4 + wv;
  if (n >= NN) return;
  ushort4 f = *reinterpret_cast<const ushort4*>(feat + (size_t)n * FH + lane * 4);
  float4 al = *reinterpret_cast<const float4*>(&attn_l[lane * 4]);
  float4 ar = *reinterpret_cast<const float4*>(&attn_r[lane * 4]);
  float fx = b2f(f.x), fy = b2f(f.y), fz = b2f(f.z), fw = b2f(f.w);
  float pl = fx * al.x + fy * al.y + fz * al.z + fw * al.w;
  float pr = fx * ar.x + fy * ar.y + fz * ar.z + fw * ar.w;
  #pragma unroll
  for (int d = 1; d < 16; d <<= 1){
    pl += __shfl_xor(pl, d);
    pr += __shfl_xor(pr, d);
  }
  if ((lane & 15) == 0){
    el[n * 4 + (lane >> 4)] = pl;
    er[n * 4 + (lane >> 4)] = pr;
  }
}

// ---------------- fused single-pass online-softmax aggregation ----------------
template<int LAYER>
__global__ __launch_bounds__(256) void k_agg(const u16* __restrict__ feat,
    const float* __restrict__ el, const float* __restrict__ er,
    const int* __restrict__ offs, const int* __restrict__ csrc,
    const float* __restrict__ bias, void* __restrict__ outv)
{
  __shared__ volatile float s_ex[4][64][4];
  __shared__ volatile int   s_src[4][64];
  int wv = threadIdx.x >> 6, lane = threadIdx.x & 63;
  int n = blockIdx.x * 4 + wv;
  if (n >= NN) return;
  int e0 = offs[n];
  int deg = offs[n + 1] - e0;
  int h = lane >> 4;
  float4 er4 = *reinterpret_cast<const float4*>(&er[n * 4]);

  float m_own = -1e30f, srun = 0.f;
  float a0 = 0.f, a1 = 0.f, a2 = 0.f, a3 = 0.f;

  for (int base = 0; base < deg; base += 64){
    int cnt = min(64, deg - base);
    float e0h, e1h, e2h, e3h;
    if (lane < cnt){
      int sj = csrc[e0 + base + lane];
      float4 l4 = *reinterpret_cast<const float4*>(&el[sj * 4]);
      e0h = leaky(l4.x + er4.x); e1h = leaky(l4.y + er4.y);
      e2h = leaky(l4.z + er4.z); e3h = leaky(l4.w + er4.w);
      s_src[wv][lane] = sj;
    } else {
      e0h = e1h = e2h = e3h = -1e30f;
    }
    float c0 = e0h, c1 = e1h, c2 = e2h, c3 = e3h;
    #pragma unroll
    for (int d = 1; d < 64; d <<= 1){
      c0 = fmaxf(c0, __shfl_xor(c0, d)); c1 = fmaxf(c1, __shfl_xor(c1, d));
      c2 = fmaxf(c2, __shfl_xor(c2, d)); c3 = fmaxf(c3, __shfl_xor(c3, d));
    }
    float nm0 = fmaxf(__shfl(m_own,  0), c0);
    float nm1 = fmaxf(__shfl(m_own, 16), c1);
    float nm2 = fmaxf(__shfl(m_own, 32), c2);
    float nm3 = fmaxf(__shfl(m_own, 48), c3);
    float ex0 = __expf(e0h - nm0), ex1 = __expf(e1h - nm1);
    float ex2 = __expf(e2h - nm2), ex3 = __expf(e3h - nm3);
    s_ex[wv][lane][0] = ex0; s_ex[wv][lane][1] = ex1;
    s_ex[wv][lane][2] = ex2; s_ex[wv][lane][3] = ex3;
    float t0 = ex0, t1 = ex1, t2 = ex2, t3 = ex3;
    #pragma unroll
    for (int d = 1; d < 64; d <<= 1){
      t0 += __shfl_xor(t0, d); t1 += __shfl_xor(t1, d);
      t2 += __shfl_xor(t2, d); t3 += __shfl_xor(t3, d);
    }
    float nm_own = (h == 0) ? nm0 : (h == 1) ? nm1 : (h == 2) ? nm2 : nm3;
    float sc_own = (h == 0) ? t0  : (h == 1) ? t1  : (h == 2) ? t2  : t3;
    float f = __expf(m_own - nm_own);
    srun = srun * f + sc_own;
    a0 *= f; a1 *= f; a2 *= f; a3 *= f;
    m_own = nm_own;
    #pragma unroll 2
    for (int jj = 0; jj < cnt; jj++){
      int sj = s_src[wv][jj];
      float w = s_ex[wv][jj][h];
      ushort4 fv = *reinterpret_cast<const ushort4*>(feat + (size_t)sj * FH + lane * 4);
      a0 = fmaf(w, b2f(fv.x), a0);
      a1 = fmaf(w, b2f(fv.y), a1);
      a2 = fmaf(w, b2f(fv.z), a2);
      a3 = fmaf(w, b2f(fv.w), a3);
    }
  }

  float inv = (deg > 0) ? 1.f / srun : 0.f;
  float4 bv = *reinterpret_cast<const float4*>(&bias[lane * 4]);
  a0 = elu1(a0 * inv + bv.x); a1 = elu1(a1 * inv + bv.y);
  a2 = elu1(a2 * inv + bv.z); a3 = elu1(a3 * inv + bv.w);

  if (LAYER == 1){
    u16* out = (u16*)outv;
    ushort4 o; o.x = f2b(a0); o.y = f2b(a1); o.z = f2b(a2); o.w = f2b(a3);
    *reinterpret_cast<ushort4*>(out + (size_t)n * FH + lane * 4) = o;
  } else {
    float* out = (float*)outv;
    a0 += __shfl_xor(a0, 16); a0 += __shfl_xor(a0, 32);
    a1 += __shfl_xor(a1, 16); a1 += __shfl_xor(a1, 32);
    a2 += __shfl_xor(a2, 16); a2 += __shfl_xor(a2, 32);
    a3 += __shfl_xor(a3, 16); a3 += __shfl_xor(a3, 32);
    if (lane < 16){
      float4 o = make_float4(a0 * 0.25f, a1 * 0.25f, a2 * 0.25f, a3 * 0.25f);
      *reinterpret_cast<float4*>(out + (size_t)n * HID + lane * 4) = o;
    }
  }
}

// ---------------- graph sum-pooling: 1 wave per 64-node chunk ----------------
__global__ __launch_bounds__(256) void k_pool(const float* __restrict__ h2,
    const int* __restrict__ gid, float* __restrict__ pooled)
{
  int wv = threadIdx.x >> 6, lane = threadIdx.x & 63;
  int w = blockIdx.x * 4 + wv;
  int base = w * 64;
  if (base >= NN) return;
  int grp = lane >> 4, c4 = (lane & 15) * 4;
  int curg = -1;
  float4 acc = make_float4(0.f, 0.f, 0.f, 0.f);
  #pragma unroll 4
  for (int it = 0; it < 16; it++){
    int row = base + it * 4 + grp;
    if (row >= NN) break;
    int g = gid[row];
    if (g != curg){
      if (curg >= 0){
        atomicAdd(&pooled[curg * HID + c4 + 0], acc.x);
        atomicAdd(&pooled[curg * HID + c4 + 1], acc.y);
        atomicAdd(&pooled[curg * HID + c4 + 2], acc.z);
        atomicAdd(&pooled[curg * HID + c4 + 3], acc.w);
      }
      curg = g; acc = make_float4(0.f, 0.f, 0.f, 0.f);
    }
    float4 v = *reinterpret_cast<const float4*>(&h2[(size_t)row * HID + c4]);
    acc.x += v.x; acc.y += v.y; acc.z += v.z; acc.w += v.w;
  }
  if (curg >= 0){
    atomicAdd(&pooled[curg * HID + c4 + 0], acc.x);
    atomicAdd(&pooled[curg * HID + c4 + 1], acc.y);
    atomicAdd(&pooled[curg * HID + c4 + 2], acc.z);
    atomicAdd(&pooled[curg * HID + c4 + 3], acc.w);
  }
}

// ---------------- final FC ----------------
__global__ void k_fc(const float* __restrict__ pooled, const float* __restrict__ fcW,
                     const float* __restrict__ fcb, float* __restrict__ out)
{
  int t = threadIdx.x;
  if (t >= NG * NOUT) return;
  int g = t / NOUT, o = t % NOUT;
  float s = fcb[o];
  for (int d = 0; d < HID; d++) s = fmaf(pooled[g * HID + d], fcW[d * NOUT + o], s);
  out[t] = s;
}

static inline size_t align_up(size_t x){ return (x + 255) & ~(size_t)255; }

extern "C" void kernel_launch(void* const* d_in, const int* in_sizes, int n_in,
                              void* d_out, int out_size, void* d_ws, size_t ws_size,
                              hipStream_t stream) {
  const float* x    = (const float*)d_in[0];
  const int*   src  = (const int*)d_in[1];
  const int*   dst  = (const int*)d_in[2];
  const int*   gid  = (const int*)d_in[3];
  const float* W1   = (const float*)d_in[4];
  const float* al1  = (const float*)d_in[5];
  const float* ar1  = (const float*)d_in[6];
  const float* b1   = (const float*)d_in[7];
  const float* W2   = (const float*)d_in[8];
  const float* al2  = (const float*)d_in[9];
  const float* ar2  = (const float*)d_in[10];
  const float* b2   = (const float*)d_in[11];
  const float* fcW  = (const float*)d_in[12];
  const float* fcb  = (const float*)d_in[13];
  float* out = (float*)d_out;

  char* p = (char*)d_ws;
  int* cnt  = (int*)p; p += align_up((size_t)NN * 4);
  int* cur  = (int*)p; p += align_up((size_t)NN * 4);
  int* offs = (int*)p; p += align_up((size_t)(NN + 1) * 4);
  int* bsum = (int*)p; p += align_up((size_t)NSB * 4);
  int* bpre = (int*)p; p += align_up((size_t)NSB * 4);
  int* csrc = (int*)p; p += align_up((size_t)NE * 4);
  u16* xh    = (u16*)p; p += align_up((size_t)MPAD * FIN * 2);
  u16* feath = (u16*)p; p += align_up((size_t)MPAD * FH * 2);
  u16* h1h   = (u16*)p; p += align_up((size_t)MPAD * FH * 2);
  float* elb = (float*)p; p += align_up((size_t)NN * NH * 4);
  float* erb = (float*)p; p += align_up((size_t)NN * NH * 4);
  float* h2  = (float*)p; p += align_up((size_t)NN * HID * 4);
  float* pooled = (float*)p; p += align_up((size_t)NG * HID * 4);
  u16* Wtc1 = (u16*)p; p += align_up((size_t)FIN * FH * 2 * 2);
  u16* Wtc2 = (u16*)p; p += align_up((size_t)FH * FH * 2 * 2);

  // zero histogram + cursor (contiguous)
  hipMemsetAsync(cnt, 0, (size_t)((char*)offs - (char*)cnt), stream);

  const int EB = (NE + 255) / 256;      // 3125
  const int NB4 = (NN + 3) / 4;         // 12500
  const int GB = MPAD / 64;             // 782

  k_hist<<<EB, 256, 0, stream>>>(dst, cnt);
  k_scan1<<<NSB, 256, 0, stream>>>(cnt, offs, bsum);
  k_scan2<<<1, 64, 0, stream>>>(bsum, bpre, offs);
  k_scan3<<<NSB, 256, 0, stream>>>(offs, bpre);
  k_scatter<<<EB, 256, 0, stream>>>(src, dst, offs, cur, csrc);

  k_f2b<<<(NN * FIN / 4 + 255) / 256, 256, 0, stream>>>(x, xh, NN * FIN);
  k_wsplit<<<(FIN * FH + 255) / 256, 256, 0, stream>>>(W1, Wtc1, FIN);
  k_wsplit<<<(FH * FH + 255) / 256, 256, 0, stream>>>(W2, Wtc2, FH);

  // layer 1
  k_gemm_bf<FIN><<<GB, 256, 0, stream>>>(xh, Wtc1, feath);
  k_scores_bf<<<NB4, 256, 0, stream>>>(feath, al1, ar1, elb, erb);
  k_agg<1><<<NB4, 256, 0, stream>>>(feath, elb, erb, offs, csrc, b1, h1h);

  // layer 2
  k_gemm_bf<FH><<<GB, 256, 0, stream>>>(h1h, Wtc2, feath);
  k_scores_bf<<<NB4, 256, 0, stream>>>(feath, al2, ar2, elb, erb);
  k_agg<2><<<NB4, 256, 0, stream>>>(feath, elb, erb, offs, csrc, b2, h2);

  // pooling + FC
  hipMemsetAsync(pooled, 0, (size_t)NG * HID * 4, stream);
  k_pool<<<(NN + 255) / 256, 256, 0, stream>>>(h2, gid, pooled);
  k_fc<<<1, 640, 0, stream>>>(pooled, fcW, fcb, out);
}